// Round 6
// baseline (238.709 us; speedup 1.0000x reference)
//
#include <hip/hip_runtime.h>

// B=2, S=2048, D=1024, H=16, DK=DV=64. M = B*S = 4096.
// Reference reshape (B,S,H*DK)->(B,H,S,DK) is a raw reinterpret: chunk
// c = flat>>17 is "head" c, viewed as [2048][64].
//
// SESSION FINDINGS:
//  - __builtin_amdgcn_exp2f gave absmax~0.72 (R3,R6); __expf passes. Banned.
//  - Q pre-scaled by 0.125f (exact pow2) in QKV epilogue.
//  - PV via 16x16x16 MFMA regressed (R8); cp16+dbuf GEMM regressed (R9):
//    register prefetch + one barrier per K-iter wins.
//  - ~6-7us per kernel boundary; R4 budget: kernels ~110us of 198 total.
//  - R11 REGRESSED: 128-row q-blocks spilled. R13 REGRESSED: K direct from
//    global = VMEM latency on QK^T critical path; keep K in LDS.
//  - R13 VALIDATED slot-permuted PV: MFMA contracts slot-wise; A slot
//    (quad,j) may hold any k as long as B slot agrees.
//  - R14 (41.9us flash, 198.2 total): y->qb balance permutation -> every
//    stride-256 CU class gets qb {31-y0, y0, 23-y0, y0+8} = 34 tiles.
//  - R15 FAILED correctness: tr_read lane mapping wrong. Derived true
//    semantics from m156: out[l][j] = elem (l16&3) of the 64b word at the
//    address supplied by lane s=4j+(l16>>2) of the same 16-lane group
//    (per-lane 4-contig-short reads, HW 16x4 transpose per group).
//  - R16 (this): vtrans deleted again, with corrected supplier pattern:
//    V natural [k][dv] in LDS, row-XOR swizzle byte = k*128+(w^((k&3)<<5))
//    (write side stays linear b128; one tr_read's 4 rows spread over all
//    32 banks). Supplier lane s -> V[32kk+16h+4quad+(s>>2)][c2*16+4(s&3)]
//    => out[l][j] = V[32kk+16h+4quad+j][c2*16+l16] = R13 slot map.
//    A-frag = own cvt_pk(exp) words, no cross-lane ops.

typedef __attribute__((ext_vector_type(8))) __bf16 bf16x8;
typedef __attribute__((ext_vector_type(8))) unsigned short ushort8;
typedef __attribute__((ext_vector_type(4))) unsigned short u16x4;
typedef __attribute__((ext_vector_type(4))) float f32x4;
typedef __attribute__((ext_vector_type(4))) unsigned int u32x4;

static __device__ __forceinline__ unsigned short f2bf(float f) {
    unsigned u = __builtin_bit_cast(unsigned, f);
    u += 0x7fffu + ((u >> 16) & 1u);
    return (unsigned short)(u >> 16);
}

static __device__ __forceinline__ float bf2f(unsigned short u) {
    return __builtin_bit_cast(float, (unsigned)u << 16);
}

// pack two f32 -> one u32 holding (bf16(lo) | bf16(hi)<<16), RNE
static __device__ __forceinline__ unsigned cvt_pk_bf16(float lo, float hi) {
    unsigned r;
    asm("v_cvt_pk_bf16_f32 %0, %1, %2" : "=v"(r) : "v"(lo), "v"(hi));
    return r;
}

// Fused prep: z<4 -> transpose+cast weight z into WT + z*2^20 ([n][k] bf16);
// z==4 -> cast x slab to bf16. Grid (16,16,5) x 256.
__global__ __launch_bounds__(256) void prep_kernel(
    const float* __restrict__ x,
    const float* __restrict__ Wq, const float* __restrict__ Wk,
    const float* __restrict__ Wv, const float* __restrict__ Wo,
    unsigned short* __restrict__ xb, unsigned short* __restrict__ WT)
{
    const int tid = threadIdx.x;
    const int z = blockIdx.z;
    if (z == 4) {
        const int bid = blockIdx.y * 16 + blockIdx.x;      // 0..255
        const int base = bid * 4096 + tid;
        #pragma unroll
        for (int it = 0; it < 16; it++) {
            int i = base + it * 256;
            float4 v = ((const float4*)x)[i];
            ushort4 o;
            o.x = f2bf(v.x); o.y = f2bf(v.y); o.z = f2bf(v.z); o.w = f2bf(v.w);
            ((ushort4*)xb)[i] = o;
        }
        return;
    }
    const float* src = (z == 0) ? Wq : (z == 1) ? Wk : (z == 2) ? Wv : Wo;
    unsigned short* dst = WT + ((size_t)z << 20);
    __shared__ __align__(16) unsigned short t[64 * 68];
    const int n0 = blockIdx.x * 64, k0 = blockIdx.y * 64;
    #pragma unroll
    for (int u = 0; u < 4; u++) {
        int e = u * 256 + tid;
        int r = e >> 4, c4 = (e & 15) * 4;
        float4 v = *(const float4*)(src + (k0 + r) * 1024 + n0 + c4);
        ushort4 o;
        o.x = f2bf(v.x); o.y = f2bf(v.y); o.z = f2bf(v.z); o.w = f2bf(v.w);
        *(ushort4*)(t + r * 68 + c4) = o;
    }
    __syncthreads();
    #pragma unroll
    for (int u = 0; u < 4; u++) {
        int e = u * 256 + tid;
        int rn = e >> 4, ck = (e & 15) * 4;
        ushort4 o;
        o.x = t[(ck + 0) * 68 + rn];
        o.y = t[(ck + 1) * 68 + rn];
        o.z = t[(ck + 2) * 68 + rn];
        o.w = t[(ck + 3) * 68 + rn];
        *(ushort4*)(dst + (n0 + rn) * 1024 + k0 + ck) = o;
    }
}

// 128x128-tile GEMM, BK=32, 4 waves (2x2). Register-prefetch + dbuf LDS,
// one barrier per K-iteration (R7-proven).
// mode 0 (QKV, N=3072): which = n0g>>10 selects outQ/outK/outV; Q scaled 0.125.
// mode 1 (out-proj, N=1024): outQ = bf16(acc + bias + resid).
__global__ __launch_bounds__(256, 3) void gemm_kernel(
    const unsigned short* __restrict__ A,
    const unsigned short* __restrict__ Bt,
    const float* __restrict__ b0, const float* __restrict__ b1, const float* __restrict__ b2,
    unsigned short* __restrict__ outQ, unsigned short* __restrict__ outK,
    unsigned short* __restrict__ outV,
    const float* __restrict__ resid, int mode)
{
    __shared__ __align__(16) unsigned short As[2][128 * 32];
    __shared__ __align__(16) unsigned short Bs[2][128 * 32];
    const int tid = threadIdx.x;
    const int lane = tid & 63, wave = tid >> 6;
    const int quad = lane >> 4, l16 = lane & 15;
    const int wm = wave >> 1, wn = wave & 1;
    const int row0 = blockIdx.y * 128, n0g = blockIdx.x * 128;

    const int sr = tid >> 2;
    const int sc = (tid & 3) * 8;
    const unsigned short* Ag0 = A + (size_t)(row0 + sr) * 1024 + sc;
    const unsigned short* Ag1 = A + (size_t)(row0 + 64 + sr) * 1024 + sc;
    const unsigned short* Bg0 = Bt + (size_t)(n0g + sr) * 1024 + sc;
    const unsigned short* Bg1 = Bt + (size_t)(n0g + 64 + sr) * 1024 + sc;

    {
        ushort8 a0 = *(const ushort8*)(Ag0);
        ushort8 a1 = *(const ushort8*)(Ag1);
        ushort8 bv0 = *(const ushort8*)(Bg0);
        ushort8 bv1 = *(const ushort8*)(Bg1);
        *(ushort8*)(As[0] + sr * 32 + sc) = a0;
        *(ushort8*)(As[0] + (64 + sr) * 32 + sc) = a1;
        *(ushort8*)(Bs[0] + sr * 32 + sc) = bv0;
        *(ushort8*)(Bs[0] + (64 + sr) * 32 + sc) = bv1;
    }
    __syncthreads();

    f32x4 acc[4][4] = {};
    #pragma unroll 2
    for (int it = 0; it < 32; ++it) {
        const int cur = it & 1;
        ushort8 na0, na1, nb0, nb1;
        if (it < 31) {
            const int k0 = (it + 1) * 32;
            na0 = *(const ushort8*)(Ag0 + k0);
            na1 = *(const ushort8*)(Ag1 + k0);
            nb0 = *(const ushort8*)(Bg0 + k0);
            nb1 = *(const ushort8*)(Bg1 + k0);
        }
        bf16x8 af[4], bfr[4];
        #pragma unroll
        for (int i = 0; i < 4; i++)
            af[i] = *(const bf16x8*)(As[cur] + (wm * 64 + i * 16 + l16) * 32 + quad * 8);
        #pragma unroll
        for (int j = 0; j < 4; j++)
            bfr[j] = *(const bf16x8*)(Bs[cur] + (wn * 64 + j * 16 + l16) * 32 + quad * 8);
        #pragma unroll
        for (int i = 0; i < 4; i++)
            #pragma unroll
            for (int j = 0; j < 4; j++)
                acc[i][j] = __builtin_amdgcn_mfma_f32_16x16x32_bf16(af[i], bfr[j], acc[i][j], 0, 0, 0);
        if (it < 31) {
            const int nxt = cur ^ 1;
            *(ushort8*)(As[nxt] + sr * 32 + sc) = na0;
            *(ushort8*)(As[nxt] + (64 + sr) * 32 + sc) = na1;
            *(ushort8*)(Bs[nxt] + sr * 32 + sc) = nb0;
            *(ushort8*)(Bs[nxt] + (64 + sr) * 32 + sc) = nb1;
            __syncthreads();
        }
    }

    if (mode == 0) {
        const int which = n0g >> 10;
        const float* bp = (which == 0) ? b0 : (which == 1) ? b1 : b2;
        unsigned short* op = (which == 0) ? outQ : (which == 1) ? outK : outV;
        const float scl = (which == 0) ? 0.125f : 1.0f;
        #pragma unroll
        for (int i = 0; i < 4; i++)
            #pragma unroll
            for (int j = 0; j < 4; j++) {
                int c = (n0g + wn * 64 + j * 16 + l16) & 1023;
                float bj = bp[c];
                #pragma unroll
                for (int r = 0; r < 4; r++) {
                    int r_g = row0 + wm * 64 + i * 16 + quad * 4 + r;
                    op[(size_t)r_g * 1024 + c] = f2bf((acc[i][j][r] + bj) * scl);
                }
            }
    } else {
        #pragma unroll
        for (int i = 0; i < 4; i++)
            #pragma unroll
            for (int j = 0; j < 4; j++) {
                int c_g = n0g + wn * 64 + j * 16 + l16;
                float bj = b0[c_g];
                #pragma unroll
                for (int r = 0; r < 4; r++) {
                    int r_g = row0 + wm * 64 + i * 16 + quad * 4 + r;
                    size_t idx = (size_t)r_g * 1024 + c_g;
                    outQ[idx] = f2bf(acc[i][j][r] + bj + resid[idx]);
                }
            }
    }
}

// Causal flash attention, S^T formulation, in-register P, HW-transpose V.
// 64-row Q blocks, 4 waves x 16 q-rows, grid (32,32), y->qb balanced.
// K staged in Kt[128][72] (register-prefetch dbuf, conflict-free b128).
// V staged from NATURAL [pos][dv] into Vl with row-XOR swizzle:
//   element (k,d) at byte k*128 + ((2d) ^ ((k&3)<<5)); b128 writes linear.
// PV B-frag via ds_read_b64_tr_b16 (2 per (kk,c2)):
//   supplier lane s (group quad) addr -> V[32kk+16h+4quad+(s>>2)]
//   [c2*16+4(s&3)]; HW 16x4 group transpose delivers
//   out[l][j] = V[32kk+16h+4quad+j][c2*16+l16]  (R13 slot map).
// PV A-frag: slot(quad,j<4)=own pE[j] (c=2kk), slot(quad,j>=4)=own pO
//   (c=2kk+1). 4x cvt_pk, no cross-lane ops.
__global__ __launch_bounds__(256, 4) void flash_kernel(
    const unsigned short* __restrict__ Q,
    const unsigned short* __restrict__ K,
    const unsigned short* __restrict__ Vn,
    unsigned short* __restrict__ Ctx)
{
    __shared__ __align__(16) unsigned short Kt[128 * 72];  // [kpos][dk]
    __shared__ __align__(16) unsigned short Vl[128 * 64];  // swizzled natural V
    const int tid = threadIdx.x;
    const int lane = tid & 63, wave = tid >> 6;
    const int quad = lane >> 4, l16 = lane & 15;
    const int y = blockIdx.y;
    const int qb = (y < 8) ? (31 - y) : (y < 16) ? (y - 8)
                 : (y < 24) ? (39 - y) : (y - 16);
    const int q0 = qb * 64;
    const long base = (long)blockIdx.x * 131072;
    const int nt = (qb + 2) >> 1;

    bf16x8 qa[2];
    #pragma unroll
    for (int h = 0; h < 2; h++)
        qa[h] = *(const bf16x8*)(Q + base + (q0 + wave * 16 + l16) * 64 + h * 32 + quad * 8);

    f32x4 o[4] = {};
    float l_one = 0.f;
    const int qpos = q0 + wave * 16 + l16;

    // V staging: e = u*256+tid -> krow = u*32 + (tid>>3), w = (tid&7)*16 B.
    // krow&3 = (tid>>3)&3, constant across u -> precompute swizzled w.
    const int vk = tid >> 3;
    const int vws = ((tid & 7) * 16) ^ (((tid >> 3) & 3) << 5);  // swizzled byte-in-row
    const int vwn = (tid & 7) * 8;                               // natural shorts-in-row
    // tr_read per-lane supplier base (this lane IS supplier s = l16, group quad):
    //   row part (4*quad + (l16>>2))*128, in-row (l16&3)*8 bytes,
    //   per c2: + (c2*32 ^ ((l16>>2)<<5))   [c2*32 bits 5-6 disjoint from (l16&3)*8]
    const unsigned vbase = (unsigned)(size_t)(const void*)Vl;
    const unsigned Ab = vbase + (unsigned)((4 * quad + (l16 >> 2)) * 128 + (l16 & 3) * 8);
    unsigned AbC[4];
    #pragma unroll
    for (int c2 = 0; c2 < 4; c2++)
        AbC[c2] = Ab + ((unsigned)(c2 * 32) ^ (unsigned)((l16 >> 2) << 5));

    // stage tile 0
    #pragma unroll
    for (int u = 0; u < 4; u++) {
        int e = u * 256 + tid;
        int r = e >> 3, c = (e & 7) * 8;
        *(ushort8*)(Kt + r * 72 + c) = *(const ushort8*)(K + base + (long)r * 64 + c);
        int kr = u * 32 + vk;
        *(ushort8*)((char*)Vl + kr * 128 + vws) =
            *(const ushort8*)(Vn + base + (long)kr * 64 + vwn);
    }
    __syncthreads();

    for (int t = 0; t < nt; t++) {
        ushort8 nk[4], nv[4];
        if (t + 1 < nt) {
            const int k1 = (t + 1) * 128;
            #pragma unroll
            for (int u = 0; u < 4; u++) {
                int e = u * 256 + tid;
                int r = e >> 3, c = (e & 7) * 8;
                nk[u] = *(const ushort8*)(K + base + (long)(k1 + r) * 64 + c);
                nv[u] = *(const ushort8*)(Vn + base + (long)(k1 + u * 32 + vk) * 64 + vwn);
            }
        }
        const int k0 = t * 128;
        const bool diag = (t == nt - 1);
        // wave w needs kpos up to q0+16w+15; pairs kk<=kkmax.
        const int kkmax = diag ? ((q0 - k0 + wave * 16 + 15) >> 5) : 3;

        #pragma unroll
        for (int kk = 0; kk < 4; kk++) {
            if (kk <= kkmax) {
                const int cE = kk * 2, cO = kk * 2 + 1;
                f32x4 aE = {}, aO = {};
                {
                    bf16x8 kb0 = *(const bf16x8*)(Kt + (cE * 16 + l16) * 72 + quad * 8);
                    bf16x8 kb1 = *(const bf16x8*)(Kt + (cE * 16 + l16) * 72 + 32 + quad * 8);
                    aE = __builtin_amdgcn_mfma_f32_16x16x32_bf16(kb0, qa[0], aE, 0, 0, 0);
                    aE = __builtin_amdgcn_mfma_f32_16x16x32_bf16(kb1, qa[1], aE, 0, 0, 0);
                }
                {
                    bf16x8 kb0 = *(const bf16x8*)(Kt + (cO * 16 + l16) * 72 + quad * 8);
                    bf16x8 kb1 = *(const bf16x8*)(Kt + (cO * 16 + l16) * 72 + 32 + quad * 8);
                    aO = __builtin_amdgcn_mfma_f32_16x16x32_bf16(kb0, qa[0], aO, 0, 0, 0);
                    aO = __builtin_amdgcn_mfma_f32_16x16x32_bf16(kb1, qa[1], aO, 0, 0, 0);
                }
                // Issue the 8 V transpose-reads now; latency hides under exp.
                u16x4 tv[4][2];
                #pragma unroll
                for (int c2 = 0; c2 < 4; c2++) {
                    unsigned a = AbC[c2] + (unsigned)(kk * 4096);
                    asm volatile("ds_read_b64_tr_b16 %0, %1"
                                 : "=v"(tv[c2][0]) : "v"(a));
                    asm volatile("ds_read_b64_tr_b16 %0, %1 offset:2048"
                                 : "=v"(tv[c2][1]) : "v"(a));
                }
                float pE[4], pO[4];
                #pragma unroll
                for (int r = 0; r < 4; r++) {
                    float e1 = __expf(aE[r]);
                    float e2 = __expf(aO[r]);
                    if (diag) {
                        int kE = k0 + cE * 16 + quad * 4 + r;
                        int kO = k0 + cO * 16 + quad * 4 + r;
                        e1 = (kE > qpos) ? 0.f : e1;
                        e2 = (kO > qpos) ? 0.f : e2;
                    }
                    pE[r] = e1; pO[r] = e2;
                }
                l_one += (pE[0] + pE[1]) + (pE[2] + pE[3])
                       + (pO[0] + pO[1]) + (pO[2] + pO[3]);
                u32x4 pu;
                pu[0] = cvt_pk_bf16(pE[0], pE[1]);
                pu[1] = cvt_pk_bf16(pE[2], pE[3]);
                pu[2] = cvt_pk_bf16(pO[0], pO[1]);
                pu[3] = cvt_pk_bf16(pO[2], pO[3]);
                bf16x8 pa = __builtin_bit_cast(bf16x8, pu);
                asm volatile("s_waitcnt lgkmcnt(0)" ::: "memory");
                __builtin_amdgcn_sched_barrier(0);
                #pragma unroll
                for (int c2 = 0; c2 < 4; c2++) {
                    ushort8 vv;
                    vv[0] = tv[c2][0][0]; vv[1] = tv[c2][0][1];
                    vv[2] = tv[c2][0][2]; vv[3] = tv[c2][0][3];
                    vv[4] = tv[c2][1][0]; vv[5] = tv[c2][1][1];
                    vv[6] = tv[c2][1][2]; vv[7] = tv[c2][1][3];
                    bf16x8 vb = __builtin_bit_cast(bf16x8, vv);
                    o[c2] = __builtin_amdgcn_mfma_f32_16x16x32_bf16(pa, vb, o[c2], 0, 0, 0);
                }
            }
        }
        __syncthreads();
        if (t + 1 < nt) {
            #pragma unroll
            for (int u = 0; u < 4; u++) {
                int e = u * 256 + tid;
                int r = e >> 3, c = (e & 7) * 8;
                *(ushort8*)(Kt + r * 72 + c) = nk[u];
                int kr = u * 32 + vk;
                *(ushort8*)((char*)Vl + kr * 128 + vws) = nv[u];
            }
            __syncthreads();
        }
    }

    l_one += __shfl_xor(l_one, 16, 64);
    l_one += __shfl_xor(l_one, 32, 64);
    float rinv[4];
    #pragma unroll
    for (int r = 0; r < 4; r++)
        rinv[r] = 1.0f / __shfl(l_one, quad * 4 + r, 16);
    #pragma unroll
    for (int c2 = 0; c2 < 4; c2++)
        #pragma unroll
        for (int r = 0; r < 4; r++) {
            int row = q0 + wave * 16 + quad * 4 + r;
            Ctx[base + (long)row * 64 + c2 * 16 + l16] = f2bf(o[c2][r] * rinv[r]);
        }
}

// LayerNorm over bf16 input rows (out-proj+resid already applied), fp32 out.
__global__ __launch_bounds__(256) void ln_kernel(const unsigned short* __restrict__ inp,
                                                 const float* __restrict__ gamma,
                                                 const float* __restrict__ beta,
                                                 float* __restrict__ out)
{
    __shared__ float ssum[4], ssq[4];
    const int row = blockIdx.x;
    const int tid = threadIdx.x;
    ushort4 uv = ((const ushort4*)(inp + (size_t)row * 1024))[tid];
    float vx = bf2f(uv.x), vy = bf2f(uv.y), vz = bf2f(uv.z), vw = bf2f(uv.w);
    float s = vx + vy + vz + vw;
    float q = vx * vx + vy * vy + vz * vz + vw * vw;
    #pragma unroll
    for (int off = 32; off >= 1; off >>= 1) {
        s += __shfl_xor(s, off, 64);
        q += __shfl_xor(q, off, 64);
    }
    if ((tid & 63) == 0) { ssum[tid >> 6] = s; ssq[tid >> 6] = q; }
    __syncthreads();
    float ts = ssum[0] + ssum[1] + ssum[2] + ssum[3];
    float tq = ssq[0] + ssq[1] + ssq[2] + ssq[3];
    float mean = ts * (1.f / 1024.f);
    float var = tq * (1.f / 1024.f) - mean * mean;
    float rinv = rsqrtf(var + 1e-5f);
    float4 g = ((const float4*)gamma)[tid];
    float4 b = ((const float4*)beta)[tid];
    float4 o;
    o.x = (vx - mean) * rinv * g.x + b.x;
    o.y = (vy - mean) * rinv * g.y + b.y;
    o.z = (vz - mean) * rinv * g.z + b.z;
    o.w = (vw - mean) * rinv * g.w + b.w;
    ((float4*)(out + (size_t)row * 1024))[tid] = o;
}

extern "C" void kernel_launch(void* const* d_in, const int* in_sizes, int n_in,
                              void* d_out, int out_size, void* d_ws, size_t ws_size,
                              hipStream_t stream) {
    const float* x     = (const float*)d_in[0];
    const float* Wk    = (const float*)d_in[1];
    const float* bk    = (const float*)d_in[2];
    const float* Wq    = (const float*)d_in[3];
    const float* bq    = (const float*)d_in[4];
    const float* Wv    = (const float*)d_in[5];
    const float* bv    = (const float*)d_in[6];
    const float* Wo    = (const float*)d_in[7];
    const float* bo    = (const float*)d_in[8];
    const float* gamma = (const float*)d_in[9];
    const float* beta  = (const float*)d_in[10];
    float* out = (float*)d_out;

    char* ws = (char*)d_ws;
    unsigned short* xb    = (unsigned short*)(ws);                 // 8 MB
    unsigned short* WqkvT = (unsigned short*)(ws + (8ull << 20));  // 8 MB (incl WoT at +6MB)
    unsigned short* Qb    = (unsigned short*)(ws + (16ull << 20)); // 8 MB
    unsigned short* Kb    = (unsigned short*)(ws + (24ull << 20)); // 8 MB
    unsigned short* Vbn   = (unsigned short*)(ws + (32ull << 20)); // 8 MB (V natural)
    unsigned short* Cb    = (unsigned short*)(ws + (40ull << 20)); // 8 MB
    unsigned short* outp  = (unsigned short*)(ws + (48ull << 20)); // 8 MB bf16
    unsigned short* WoT   = WqkvT + (3u << 20);

    dim3 pgrid(16, 16, 5);
    prep_kernel<<<pgrid, 256, 0, stream>>>(x, Wq, Wk, Wv, Wo, xb, WqkvT);

    dim3 qkvgrid(24, 32);
    gemm_kernel<<<qkvgrid, 256, 0, stream>>>(xb, WqkvT, bq, bk, bv,
                                             Qb, Kb, Vbn, nullptr, 0);

    dim3 fgrid(32, 32);
    flash_kernel<<<fgrid, 256, 0, stream>>>(Qb, Kb, Vbn, Cb);

    dim3 ogrid(8, 32);
    gemm_kernel<<<ogrid, 256, 0, stream>>>(Cb, WoT, bo, nullptr, nullptr,
                                           outp, nullptr, nullptr, x, 1);

    ln_kernel<<<4096, 256, 0, stream>>>(outp, gamma, beta, out);
}

// Round 7
// 221.598 us; speedup vs baseline: 1.0772x; 1.0772x over previous
//
#include <hip/hip_runtime.h>

// B=2, S=2048, D=1024, H=16, DK=DV=64. M = B*S = 4096.
// Reference reshape (B,S,H*DK)->(B,H,S,DK) is a raw reinterpret: chunk
// c = flat>>17 is "head" c, viewed as [2048][64].
//
// SESSION FINDINGS:
//  - __builtin_amdgcn_exp2f gave absmax~0.72 (R3,R6); __expf passes. Banned.
//  - Q pre-scaled by 0.125f (exact pow2) in QKV epilogue.
//  - PV via 16x16x16 MFMA regressed (R8); cp16+dbuf GEMM regressed (R9):
//    register prefetch + one barrier per K-iter wins.
//  - ~6-7us per kernel boundary; R4 budget: kernels ~110us of 198 total.
//  - R11 REGRESSED: 128-row q-blocks spilled. R13 REGRESSED: K direct from
//    global = VMEM latency on QK^T critical path; keep K in LDS.
//  - R13 VALIDATED slot-permuted PV: MFMA contracts slot-wise; A slot
//    (quad,j) may hold any k as long as B slot agrees.
//  - R14 (41.9us flash, 198.2 total): y->qb balance permutation -> every
//    stride-256 CU class gets qb {31-y0, y0, 23-y0, y0+8} = 34 tiles.
//  - R15 FAILED correctness: tr_read lane mapping wrong. True semantics
//    (m156): out[l][j] = elem (l16&3) of the 64b word at the address of
//    supplier lane s=4j+(l16>>2) in the same 16-lane group.
//  - R16: corrected supplier mapping PASSED (absmax 0.03125) but flash
//    90us: WRITE 14->164MB at unchanged VGPR=64 = rule-#20 localMem —
//    tv[4][2]/AbC[4] arrays written via asm outputs stayed as allocas,
//    scratch round-trip every kk. Schedule itself validated.
//  - R17 (this): identical structure, asm path SCALARIZED: named u16x4
//    tA0..tD1, inline addresses via (c2^s2)<<5, shufflevector concat.
//    No arrays near asm. Expect WRITE back to ~14MB, flash ~42us.

typedef __attribute__((ext_vector_type(8))) __bf16 bf16x8;
typedef __attribute__((ext_vector_type(8))) unsigned short ushort8;
typedef __attribute__((ext_vector_type(4))) unsigned short u16x4;
typedef __attribute__((ext_vector_type(4))) float f32x4;
typedef __attribute__((ext_vector_type(4))) unsigned int u32x4;

static __device__ __forceinline__ unsigned short f2bf(float f) {
    unsigned u = __builtin_bit_cast(unsigned, f);
    u += 0x7fffu + ((u >> 16) & 1u);
    return (unsigned short)(u >> 16);
}

static __device__ __forceinline__ float bf2f(unsigned short u) {
    return __builtin_bit_cast(float, (unsigned)u << 16);
}

// pack two f32 -> one u32 holding (bf16(lo) | bf16(hi)<<16), RNE
static __device__ __forceinline__ unsigned cvt_pk_bf16(float lo, float hi) {
    unsigned r;
    asm("v_cvt_pk_bf16_f32 %0, %1, %2" : "=v"(r) : "v"(lo), "v"(hi));
    return r;
}

// Fused prep: z<4 -> transpose+cast weight z into WT + z*2^20 ([n][k] bf16);
// z==4 -> cast x slab to bf16. Grid (16,16,5) x 256.
__global__ __launch_bounds__(256) void prep_kernel(
    const float* __restrict__ x,
    const float* __restrict__ Wq, const float* __restrict__ Wk,
    const float* __restrict__ Wv, const float* __restrict__ Wo,
    unsigned short* __restrict__ xb, unsigned short* __restrict__ WT)
{
    const int tid = threadIdx.x;
    const int z = blockIdx.z;
    if (z == 4) {
        const int bid = blockIdx.y * 16 + blockIdx.x;      // 0..255
        const int base = bid * 4096 + tid;
        #pragma unroll
        for (int it = 0; it < 16; it++) {
            int i = base + it * 256;
            float4 v = ((const float4*)x)[i];
            ushort4 o;
            o.x = f2bf(v.x); o.y = f2bf(v.y); o.z = f2bf(v.z); o.w = f2bf(v.w);
            ((ushort4*)xb)[i] = o;
        }
        return;
    }
    const float* src = (z == 0) ? Wq : (z == 1) ? Wk : (z == 2) ? Wv : Wo;
    unsigned short* dst = WT + ((size_t)z << 20);
    __shared__ __align__(16) unsigned short t[64 * 68];
    const int n0 = blockIdx.x * 64, k0 = blockIdx.y * 64;
    #pragma unroll
    for (int u = 0; u < 4; u++) {
        int e = u * 256 + tid;
        int r = e >> 4, c4 = (e & 15) * 4;
        float4 v = *(const float4*)(src + (k0 + r) * 1024 + n0 + c4);
        ushort4 o;
        o.x = f2bf(v.x); o.y = f2bf(v.y); o.z = f2bf(v.z); o.w = f2bf(v.w);
        *(ushort4*)(t + r * 68 + c4) = o;
    }
    __syncthreads();
    #pragma unroll
    for (int u = 0; u < 4; u++) {
        int e = u * 256 + tid;
        int rn = e >> 4, ck = (e & 15) * 4;
        ushort4 o;
        o.x = t[(ck + 0) * 68 + rn];
        o.y = t[(ck + 1) * 68 + rn];
        o.z = t[(ck + 2) * 68 + rn];
        o.w = t[(ck + 3) * 68 + rn];
        *(ushort4*)(dst + (n0 + rn) * 1024 + k0 + ck) = o;
    }
}

// 128x128-tile GEMM, BK=32, 4 waves (2x2). Register-prefetch + dbuf LDS,
// one barrier per K-iteration (R7-proven).
// mode 0 (QKV, N=3072): which = n0g>>10 selects outQ/outK/outV; Q scaled 0.125.
// mode 1 (out-proj, N=1024): outQ = bf16(acc + bias + resid).
__global__ __launch_bounds__(256, 3) void gemm_kernel(
    const unsigned short* __restrict__ A,
    const unsigned short* __restrict__ Bt,
    const float* __restrict__ b0, const float* __restrict__ b1, const float* __restrict__ b2,
    unsigned short* __restrict__ outQ, unsigned short* __restrict__ outK,
    unsigned short* __restrict__ outV,
    const float* __restrict__ resid, int mode)
{
    __shared__ __align__(16) unsigned short As[2][128 * 32];
    __shared__ __align__(16) unsigned short Bs[2][128 * 32];
    const int tid = threadIdx.x;
    const int lane = tid & 63, wave = tid >> 6;
    const int quad = lane >> 4, l16 = lane & 15;
    const int wm = wave >> 1, wn = wave & 1;
    const int row0 = blockIdx.y * 128, n0g = blockIdx.x * 128;

    const int sr = tid >> 2;
    const int sc = (tid & 3) * 8;
    const unsigned short* Ag0 = A + (size_t)(row0 + sr) * 1024 + sc;
    const unsigned short* Ag1 = A + (size_t)(row0 + 64 + sr) * 1024 + sc;
    const unsigned short* Bg0 = Bt + (size_t)(n0g + sr) * 1024 + sc;
    const unsigned short* Bg1 = Bt + (size_t)(n0g + 64 + sr) * 1024 + sc;

    {
        ushort8 a0 = *(const ushort8*)(Ag0);
        ushort8 a1 = *(const ushort8*)(Ag1);
        ushort8 bv0 = *(const ushort8*)(Bg0);
        ushort8 bv1 = *(const ushort8*)(Bg1);
        *(ushort8*)(As[0] + sr * 32 + sc) = a0;
        *(ushort8*)(As[0] + (64 + sr) * 32 + sc) = a1;
        *(ushort8*)(Bs[0] + sr * 32 + sc) = bv0;
        *(ushort8*)(Bs[0] + (64 + sr) * 32 + sc) = bv1;
    }
    __syncthreads();

    f32x4 acc[4][4] = {};
    #pragma unroll 2
    for (int it = 0; it < 32; ++it) {
        const int cur = it & 1;
        ushort8 na0, na1, nb0, nb1;
        if (it < 31) {
            const int k0 = (it + 1) * 32;
            na0 = *(const ushort8*)(Ag0 + k0);
            na1 = *(const ushort8*)(Ag1 + k0);
            nb0 = *(const ushort8*)(Bg0 + k0);
            nb1 = *(const ushort8*)(Bg1 + k0);
        }
        bf16x8 af[4], bfr[4];
        #pragma unroll
        for (int i = 0; i < 4; i++)
            af[i] = *(const bf16x8*)(As[cur] + (wm * 64 + i * 16 + l16) * 32 + quad * 8);
        #pragma unroll
        for (int j = 0; j < 4; j++)
            bfr[j] = *(const bf16x8*)(Bs[cur] + (wn * 64 + j * 16 + l16) * 32 + quad * 8);
        #pragma unroll
        for (int i = 0; i < 4; i++)
            #pragma unroll
            for (int j = 0; j < 4; j++)
                acc[i][j] = __builtin_amdgcn_mfma_f32_16x16x32_bf16(af[i], bfr[j], acc[i][j], 0, 0, 0);
        if (it < 31) {
            const int nxt = cur ^ 1;
            *(ushort8*)(As[nxt] + sr * 32 + sc) = na0;
            *(ushort8*)(As[nxt] + (64 + sr) * 32 + sc) = na1;
            *(ushort8*)(Bs[nxt] + sr * 32 + sc) = nb0;
            *(ushort8*)(Bs[nxt] + (64 + sr) * 32 + sc) = nb1;
            __syncthreads();
        }
    }

    if (mode == 0) {
        const int which = n0g >> 10;
        const float* bp = (which == 0) ? b0 : (which == 1) ? b1 : b2;
        unsigned short* op = (which == 0) ? outQ : (which == 1) ? outK : outV;
        const float scl = (which == 0) ? 0.125f : 1.0f;
        #pragma unroll
        for (int i = 0; i < 4; i++)
            #pragma unroll
            for (int j = 0; j < 4; j++) {
                int c = (n0g + wn * 64 + j * 16 + l16) & 1023;
                float bj = bp[c];
                #pragma unroll
                for (int r = 0; r < 4; r++) {
                    int r_g = row0 + wm * 64 + i * 16 + quad * 4 + r;
                    op[(size_t)r_g * 1024 + c] = f2bf((acc[i][j][r] + bj) * scl);
                }
            }
    } else {
        #pragma unroll
        for (int i = 0; i < 4; i++)
            #pragma unroll
            for (int j = 0; j < 4; j++) {
                int c_g = n0g + wn * 64 + j * 16 + l16;
                float bj = b0[c_g];
                #pragma unroll
                for (int r = 0; r < 4; r++) {
                    int r_g = row0 + wm * 64 + i * 16 + quad * 4 + r;
                    size_t idx = (size_t)r_g * 1024 + c_g;
                    outQ[idx] = f2bf(acc[i][j][r] + bj + resid[idx]);
                }
            }
    }
}

// Causal flash attention, S^T formulation, in-register P, HW-transpose V.
// 64-row Q blocks, 4 waves x 16 q-rows, grid (32,32), y->qb balanced.
// K staged in Kt[128][72] (register-prefetch dbuf, conflict-free b128).
// V staged from NATURAL [pos][dv] into Vl with row-XOR swizzle:
//   element (k,d) at byte k*128 + ((2d) ^ ((k&3)<<5)); b128 writes linear.
// PV B-frag via ds_read_b64_tr_b16 (2 per (kk,c2)):
//   supplier lane s (group quad) addr -> V[32kk+16h+4quad+(s>>2)]
//   [c2*16+4(s&3)]; HW 16x4 group transpose delivers
//   out[l][j] = V[32kk+16h+4quad+j][c2*16+l16]  (R13 slot map).
// PV A-frag: slot(quad,j<4)=own pE[j] (c=2kk), slot(quad,j>=4)=own pO
//   (c=2kk+1). 4x cvt_pk, no cross-lane ops. ALL-SCALAR asm path (R16
//   lesson: arrays near asm outputs -> localMem -> 164MB scratch).
__global__ __launch_bounds__(256, 4) void flash_kernel(
    const unsigned short* __restrict__ Q,
    const unsigned short* __restrict__ K,
    const unsigned short* __restrict__ Vn,
    unsigned short* __restrict__ Ctx)
{
    __shared__ __align__(16) unsigned short Kt[128 * 72];  // [kpos][dk]
    __shared__ __align__(16) unsigned short Vl[128 * 64];  // swizzled natural V
    const int tid = threadIdx.x;
    const int lane = tid & 63, wave = tid >> 6;
    const int quad = lane >> 4, l16 = lane & 15;
    const int y = blockIdx.y;
    const int qb = (y < 8) ? (31 - y) : (y < 16) ? (y - 8)
                 : (y < 24) ? (39 - y) : (y - 16);
    const int q0 = qb * 64;
    const long base = (long)blockIdx.x * 131072;
    const int nt = (qb + 2) >> 1;

    bf16x8 qa[2];
    #pragma unroll
    for (int h = 0; h < 2; h++)
        qa[h] = *(const bf16x8*)(Q + base + (q0 + wave * 16 + l16) * 64 + h * 32 + quad * 8);

    f32x4 o[4] = {};
    float l_one = 0.f;
    const int qpos = q0 + wave * 16 + l16;

    // V staging: e = u*256+tid -> krow = u*32 + (tid>>3), w = (tid&7)*16 B.
    // krow&3 = (tid>>3)&3, constant across u -> precompute swizzled w.
    const int vk = tid >> 3;
    const int vws = ((tid & 7) * 16) ^ (((tid >> 3) & 3) << 5);  // swizzled byte-in-row
    const int vwn = (tid & 7) * 8;                               // natural shorts-in-row
    // tr_read supplier base: this lane IS supplier s = l16, group quad:
    //   Ab = (4*quad + (l16>>2))*128 + (l16&3)*8;
    //   per (kk,c2,h): + kk*4096 + ((c2 ^ (l16>>2))<<5) + h*2048.
    const unsigned s2u = (unsigned)(l16 >> 2);
    const unsigned Ab = (unsigned)(size_t)(const void*)Vl
                      + (unsigned)((4 * quad + (l16 >> 2)) * 128 + (l16 & 3) * 8);

    // stage tile 0
    #pragma unroll
    for (int u = 0; u < 4; u++) {
        int e = u * 256 + tid;
        int r = e >> 3, c = (e & 7) * 8;
        *(ushort8*)(Kt + r * 72 + c) = *(const ushort8*)(K + base + (long)r * 64 + c);
        int kr = u * 32 + vk;
        *(ushort8*)((char*)Vl + kr * 128 + vws) =
            *(const ushort8*)(Vn + base + (long)kr * 64 + vwn);
    }
    __syncthreads();

    for (int t = 0; t < nt; t++) {
        ushort8 nk0, nk1, nk2, nk3, nv0, nv1, nv2, nv3;
        if (t + 1 < nt) {
            const int k1 = (t + 1) * 128;
            const int r = tid >> 3, c = (tid & 7) * 8;
            nk0 = *(const ushort8*)(K + base + (long)(k1 + r) * 64 + c);
            nk1 = *(const ushort8*)(K + base + (long)(k1 + 32 + r) * 64 + c);
            nk2 = *(const ushort8*)(K + base + (long)(k1 + 64 + r) * 64 + c);
            nk3 = *(const ushort8*)(K + base + (long)(k1 + 96 + r) * 64 + c);
            nv0 = *(const ushort8*)(Vn + base + (long)(k1 + vk) * 64 + vwn);
            nv1 = *(const ushort8*)(Vn + base + (long)(k1 + 32 + vk) * 64 + vwn);
            nv2 = *(const ushort8*)(Vn + base + (long)(k1 + 64 + vk) * 64 + vwn);
            nv3 = *(const ushort8*)(Vn + base + (long)(k1 + 96 + vk) * 64 + vwn);
        }
        const int k0 = t * 128;
        const bool diag = (t == nt - 1);
        // wave w needs kpos up to q0+16w+15; pairs kk<=kkmax.
        const int kkmax = diag ? ((q0 - k0 + wave * 16 + 15) >> 5) : 3;

        #pragma unroll
        for (int kk = 0; kk < 4; kk++) {
            if (kk <= kkmax) {
                const int cE = kk * 2, cO = kk * 2 + 1;
                f32x4 aE = {}, aO = {};
                {
                    bf16x8 kb0 = *(const bf16x8*)(Kt + (cE * 16 + l16) * 72 + quad * 8);
                    bf16x8 kb1 = *(const bf16x8*)(Kt + (cE * 16 + l16) * 72 + 32 + quad * 8);
                    aE = __builtin_amdgcn_mfma_f32_16x16x32_bf16(kb0, qa[0], aE, 0, 0, 0);
                    aE = __builtin_amdgcn_mfma_f32_16x16x32_bf16(kb1, qa[1], aE, 0, 0, 0);
                }
                {
                    bf16x8 kb0 = *(const bf16x8*)(Kt + (cO * 16 + l16) * 72 + quad * 8);
                    bf16x8 kb1 = *(const bf16x8*)(Kt + (cO * 16 + l16) * 72 + 32 + quad * 8);
                    aO = __builtin_amdgcn_mfma_f32_16x16x32_bf16(kb0, qa[0], aO, 0, 0, 0);
                    aO = __builtin_amdgcn_mfma_f32_16x16x32_bf16(kb1, qa[1], aO, 0, 0, 0);
                }
                // Issue 8 V transpose-reads (named scalars only);
                // latency hides under exp/cvt below.
                u16x4 tA0, tA1, tB0, tB1, tC0, tC1, tD0, tD1;
                {
                    const unsigned atr = Ab + (unsigned)(kk * 4096);
                    unsigned a0 = atr + ((0u ^ s2u) << 5);
                    unsigned a1 = atr + ((1u ^ s2u) << 5);
                    unsigned a2 = atr + ((2u ^ s2u) << 5);
                    unsigned a3 = atr + ((3u ^ s2u) << 5);
                    asm volatile("ds_read_b64_tr_b16 %0, %2\n\t"
                                 "ds_read_b64_tr_b16 %1, %2 offset:2048"
                                 : "=&v"(tA0), "=&v"(tA1) : "v"(a0));
                    asm volatile("ds_read_b64_tr_b16 %0, %2\n\t"
                                 "ds_read_b64_tr_b16 %1, %2 offset:2048"
                                 : "=&v"(tB0), "=&v"(tB1) : "v"(a1));
                    asm volatile("ds_read_b64_tr_b16 %0, %2\n\t"
                                 "ds_read_b64_tr_b16 %1, %2 offset:2048"
                                 : "=&v"(tC0), "=&v"(tC1) : "v"(a2));
                    asm volatile("ds_read_b64_tr_b16 %0, %2\n\t"
                                 "ds_read_b64_tr_b16 %1, %2 offset:2048"
                                 : "=&v"(tD0), "=&v"(tD1) : "v"(a3));
                }
                float pE0, pE1, pE2, pE3, pO0, pO1, pO2, pO3;
                {
                    float e0 = __expf(aE[0]), e1 = __expf(aE[1]);
                    float e2 = __expf(aE[2]), e3 = __expf(aE[3]);
                    float f0 = __expf(aO[0]), f1 = __expf(aO[1]);
                    float f2 = __expf(aO[2]), f3 = __expf(aO[3]);
                    if (diag) {
                        int kE = k0 + cE * 16 + quad * 4;
                        int kO = k0 + cO * 16 + quad * 4;
                        e0 = (kE + 0 > qpos) ? 0.f : e0;
                        e1 = (kE + 1 > qpos) ? 0.f : e1;
                        e2 = (kE + 2 > qpos) ? 0.f : e2;
                        e3 = (kE + 3 > qpos) ? 0.f : e3;
                        f0 = (kO + 0 > qpos) ? 0.f : f0;
                        f1 = (kO + 1 > qpos) ? 0.f : f1;
                        f2 = (kO + 2 > qpos) ? 0.f : f2;
                        f3 = (kO + 3 > qpos) ? 0.f : f3;
                    }
                    pE0 = e0; pE1 = e1; pE2 = e2; pE3 = e3;
                    pO0 = f0; pO1 = f1; pO2 = f2; pO3 = f3;
                }
                l_one += (pE0 + pE1) + (pE2 + pE3)
                       + (pO0 + pO1) + (pO2 + pO3);
                u32x4 pu;
                pu[0] = cvt_pk_bf16(pE0, pE1);
                pu[1] = cvt_pk_bf16(pE2, pE3);
                pu[2] = cvt_pk_bf16(pO0, pO1);
                pu[3] = cvt_pk_bf16(pO2, pO3);
                bf16x8 pa = __builtin_bit_cast(bf16x8, pu);
                asm volatile("s_waitcnt lgkmcnt(0)" ::: "memory");
                __builtin_amdgcn_sched_barrier(0);
                {
                    bf16x8 vb0 = __builtin_bit_cast(bf16x8,
                        __builtin_shufflevector(tA0, tA1, 0, 1, 2, 3, 4, 5, 6, 7));
                    o[0] = __builtin_amdgcn_mfma_f32_16x16x32_bf16(pa, vb0, o[0], 0, 0, 0);
                    bf16x8 vb1 = __builtin_bit_cast(bf16x8,
                        __builtin_shufflevector(tB0, tB1, 0, 1, 2, 3, 4, 5, 6, 7));
                    o[1] = __builtin_amdgcn_mfma_f32_16x16x32_bf16(pa, vb1, o[1], 0, 0, 0);
                    bf16x8 vb2 = __builtin_bit_cast(bf16x8,
                        __builtin_shufflevector(tC0, tC1, 0, 1, 2, 3, 4, 5, 6, 7));
                    o[2] = __builtin_amdgcn_mfma_f32_16x16x32_bf16(pa, vb2, o[2], 0, 0, 0);
                    bf16x8 vb3 = __builtin_bit_cast(bf16x8,
                        __builtin_shufflevector(tD0, tD1, 0, 1, 2, 3, 4, 5, 6, 7));
                    o[3] = __builtin_amdgcn_mfma_f32_16x16x32_bf16(pa, vb3, o[3], 0, 0, 0);
                }
            }
        }
        __syncthreads();
        if (t + 1 < nt) {
            const int r = tid >> 3, c = (tid & 7) * 8;
            *(ushort8*)(Kt + r * 72 + c) = nk0;
            *(ushort8*)(Kt + (32 + r) * 72 + c) = nk1;
            *(ushort8*)(Kt + (64 + r) * 72 + c) = nk2;
            *(ushort8*)(Kt + (96 + r) * 72 + c) = nk3;
            *(ushort8*)((char*)Vl + (vk) * 128 + vws) = nv0;
            *(ushort8*)((char*)Vl + (32 + vk) * 128 + vws) = nv1;
            *(ushort8*)((char*)Vl + (64 + vk) * 128 + vws) = nv2;
            *(ushort8*)((char*)Vl + (96 + vk) * 128 + vws) = nv3;
            __syncthreads();
        }
    }

    l_one += __shfl_xor(l_one, 16, 64);
    l_one += __shfl_xor(l_one, 32, 64);
    float rinv[4];
    #pragma unroll
    for (int r = 0; r < 4; r++)
        rinv[r] = 1.0f / __shfl(l_one, quad * 4 + r, 16);
    #pragma unroll
    for (int c2 = 0; c2 < 4; c2++)
        #pragma unroll
        for (int r = 0; r < 4; r++) {
            int row = q0 + wave * 16 + quad * 4 + r;
            Ctx[base + (long)row * 64 + c2 * 16 + l16] = f2bf(o[c2][r] * rinv[r]);
        }
}

// LayerNorm over bf16 input rows (out-proj+resid already applied), fp32 out.
__global__ __launch_bounds__(256) void ln_kernel(const unsigned short* __restrict__ inp,
                                                 const float* __restrict__ gamma,
                                                 const float* __restrict__ beta,
                                                 float* __restrict__ out)
{
    __shared__ float ssum[4], ssq[4];
    const int row = blockIdx.x;
    const int tid = threadIdx.x;
    ushort4 uv = ((const ushort4*)(inp + (size_t)row * 1024))[tid];
    float vx = bf2f(uv.x), vy = bf2f(uv.y), vz = bf2f(uv.z), vw = bf2f(uv.w);
    float s = vx + vy + vz + vw;
    float q = vx * vx + vy * vy + vz * vz + vw * vw;
    #pragma unroll
    for (int off = 32; off >= 1; off >>= 1) {
        s += __shfl_xor(s, off, 64);
        q += __shfl_xor(q, off, 64);
    }
    if ((tid & 63) == 0) { ssum[tid >> 6] = s; ssq[tid >> 6] = q; }
    __syncthreads();
    float ts = ssum[0] + ssum[1] + ssum[2] + ssum[3];
    float tq = ssq[0] + ssq[1] + ssq[2] + ssq[3];
    float mean = ts * (1.f / 1024.f);
    float var = tq * (1.f / 1024.f) - mean * mean;
    float rinv = rsqrtf(var + 1e-5f);
    float4 g = ((const float4*)gamma)[tid];
    float4 b = ((const float4*)beta)[tid];
    float4 o;
    o.x = (vx - mean) * rinv * g.x + b.x;
    o.y = (vy - mean) * rinv * g.y + b.y;
    o.z = (vz - mean) * rinv * g.z + b.z;
    o.w = (vw - mean) * rinv * g.w + b.w;
    ((float4*)(out + (size_t)row * 1024))[tid] = o;
}

extern "C" void kernel_launch(void* const* d_in, const int* in_sizes, int n_in,
                              void* d_out, int out_size, void* d_ws, size_t ws_size,
                              hipStream_t stream) {
    const float* x     = (const float*)d_in[0];
    const float* Wk    = (const float*)d_in[1];
    const float* bk    = (const float*)d_in[2];
    const float* Wq    = (const float*)d_in[3];
    const float* bq    = (const float*)d_in[4];
    const float* Wv    = (const float*)d_in[5];
    const float* bv    = (const float*)d_in[6];
    const float* Wo    = (const float*)d_in[7];
    const float* bo    = (const float*)d_in[8];
    const float* gamma = (const float*)d_in[9];
    const float* beta  = (const float*)d_in[10];
    float* out = (float*)d_out;

    char* ws = (char*)d_ws;
    unsigned short* xb    = (unsigned short*)(ws);                 // 8 MB
    unsigned short* WqkvT = (unsigned short*)(ws + (8ull << 20));  // 8 MB (incl WoT at +6MB)
    unsigned short* Qb    = (unsigned short*)(ws + (16ull << 20)); // 8 MB
    unsigned short* Kb    = (unsigned short*)(ws + (24ull << 20)); // 8 MB
    unsigned short* Vbn   = (unsigned short*)(ws + (32ull << 20)); // 8 MB (V natural)
    unsigned short* Cb    = (unsigned short*)(ws + (40ull << 20)); // 8 MB
    unsigned short* outp  = (unsigned short*)(ws + (48ull << 20)); // 8 MB bf16
    unsigned short* WoT   = WqkvT + (3u << 20);

    dim3 pgrid(16, 16, 5);
    prep_kernel<<<pgrid, 256, 0, stream>>>(x, Wq, Wk, Wv, Wo, xb, WqkvT);

    dim3 qkvgrid(24, 32);
    gemm_kernel<<<qkvgrid, 256, 0, stream>>>(xb, WqkvT, bq, bk, bv,
                                             Qb, Kb, Vbn, nullptr, 0);

    dim3 fgrid(32, 32);
    flash_kernel<<<fgrid, 256, 0, stream>>>(Qb, Kb, Vbn, Cb);

    dim3 ogrid(8, 32);
    gemm_kernel<<<ogrid, 256, 0, stream>>>(Cb, WoT, bo, nullptr, nullptr,
                                           outp, nullptr, nullptr, x, 1);

    ln_kernel<<<4096, 256, 0, stream>>>(outp, gamma, beta, out);
}

// Round 8
// 197.079 us; speedup vs baseline: 1.2112x; 1.1244x over previous
//
#include <hip/hip_runtime.h>

// B=2, S=2048, D=1024, H=16, DK=DV=64. M = B*S = 4096.
// Reference reshape (B,S,H*DK)->(B,H,S,DK) is a raw reinterpret: chunk
// c = flat>>17 is "head" c, viewed as [2048][64].
//
// SESSION FINDINGS:
//  - __builtin_amdgcn_exp2f gave absmax~0.72 (R3,R6); __expf passes. Banned.
//  - Q pre-scaled by 0.125f (exact pow2) in QKV epilogue.
//  - PV via 16x16x16 MFMA regressed (R8); cp16+dbuf GEMM regressed (R9):
//    register prefetch + one barrier per K-iter wins.
//  - ~6-7us per kernel boundary. R4 trace: fillBufferAligned 256MB ~42us =
//    harness workspace re-poison, not addressable. Kernel sum ~105us.
//  - R11 REGRESSED: 128-row q-blocks spilled. R13 REGRESSED: K direct from
//    global = VMEM latency on QK^T critical path; keep K in LDS.
//  - R14 (41.9us flash, 198.2 total = session best): y->qb balance
//    permutation -> every stride-256 CU class gets exactly 34 tiles.
//  - R15-R17 tr_read ARC ABANDONED: mapping correct (R16/R17 pass) but
//    8x asm tr_read + sched_barrier per kk pins ~90 live regs -> compiler
//    demotes to scratch (WRITE 14->167->120MB, flash 72-90us). vtrans
//    kernel restored; the ~11us fusion win doesn't justify the codegen
//    fight. DO NOT retry without a different register schedule.
//  - R18 (this): R4 verbatim + s_setprio(1/0) around flash MFMA clusters
//    (T5). Flash CU hosts 4 blocks at different nt (desynced phases) =
//    the m191 attn regime where setprio paid +4-7%, not the m190
//    lockstep-GEMM null. Pre-commit: null => flash local ceiling.

typedef __attribute__((ext_vector_type(8))) __bf16 bf16x8;
typedef __attribute__((ext_vector_type(8))) unsigned short ushort8;
typedef __attribute__((ext_vector_type(4))) unsigned short u16x4;
typedef __attribute__((ext_vector_type(4))) float f32x4;
typedef __attribute__((ext_vector_type(4))) unsigned int u32x4;

static __device__ __forceinline__ unsigned short f2bf(float f) {
    unsigned u = __builtin_bit_cast(unsigned, f);
    u += 0x7fffu + ((u >> 16) & 1u);
    return (unsigned short)(u >> 16);
}

static __device__ __forceinline__ float bf2f(unsigned short u) {
    return __builtin_bit_cast(float, (unsigned)u << 16);
}

// pack two f32 -> one u32 holding (bf16(lo) | bf16(hi)<<16), RNE
static __device__ __forceinline__ unsigned cvt_pk_bf16(float lo, float hi) {
    unsigned r;
    asm("v_cvt_pk_bf16_f32 %0, %1, %2" : "=v"(r) : "v"(lo), "v"(hi));
    return r;
}

// Fused prep: z<4 -> transpose+cast weight z into WT + z*2^20 ([n][k] bf16);
// z==4 -> cast x slab to bf16. Grid (16,16,5) x 256.
__global__ __launch_bounds__(256) void prep_kernel(
    const float* __restrict__ x,
    const float* __restrict__ Wq, const float* __restrict__ Wk,
    const float* __restrict__ Wv, const float* __restrict__ Wo,
    unsigned short* __restrict__ xb, unsigned short* __restrict__ WT)
{
    const int tid = threadIdx.x;
    const int z = blockIdx.z;
    if (z == 4) {
        const int bid = blockIdx.y * 16 + blockIdx.x;      // 0..255
        const int base = bid * 4096 + tid;
        #pragma unroll
        for (int it = 0; it < 16; it++) {
            int i = base + it * 256;
            float4 v = ((const float4*)x)[i];
            ushort4 o;
            o.x = f2bf(v.x); o.y = f2bf(v.y); o.z = f2bf(v.z); o.w = f2bf(v.w);
            ((ushort4*)xb)[i] = o;
        }
        return;
    }
    const float* src = (z == 0) ? Wq : (z == 1) ? Wk : (z == 2) ? Wv : Wo;
    unsigned short* dst = WT + ((size_t)z << 20);
    __shared__ __align__(16) unsigned short t[64 * 68];
    const int n0 = blockIdx.x * 64, k0 = blockIdx.y * 64;
    #pragma unroll
    for (int u = 0; u < 4; u++) {
        int e = u * 256 + tid;
        int r = e >> 4, c4 = (e & 15) * 4;
        float4 v = *(const float4*)(src + (k0 + r) * 1024 + n0 + c4);
        ushort4 o;
        o.x = f2bf(v.x); o.y = f2bf(v.y); o.z = f2bf(v.z); o.w = f2bf(v.w);
        *(ushort4*)(t + r * 68 + c4) = o;
    }
    __syncthreads();
    #pragma unroll
    for (int u = 0; u < 4; u++) {
        int e = u * 256 + tid;
        int rn = e >> 4, ck = (e & 15) * 4;
        ushort4 o;
        o.x = t[(ck + 0) * 68 + rn];
        o.y = t[(ck + 1) * 68 + rn];
        o.z = t[(ck + 2) * 68 + rn];
        o.w = t[(ck + 3) * 68 + rn];
        *(ushort4*)(dst + (n0 + rn) * 1024 + k0 + ck) = o;
    }
}

// Transpose bf16 V-projection [4096][1024] into per-chunk VT[ch][dv][pos].
__global__ __launch_bounds__(256) void vtrans_kernel(const unsigned short* __restrict__ V,
                                                     unsigned short* __restrict__ VT) {
    __shared__ __align__(16) unsigned short t[64 * 68];
    const int tid = threadIdx.x;
    const int p0 = blockIdx.x * 64;
    const long base = (long)blockIdx.y * 131072;
    #pragma unroll
    for (int u = 0; u < 2; u++) {
        int e = u * 256 + tid;
        int r = e >> 3, c8 = (e & 7) * 8;
        ushort8 v = *(const ushort8*)(V + base + (long)(p0 + r) * 64 + c8);
        *(ushort8*)(t + r * 68 + c8) = v;
    }
    __syncthreads();
    #pragma unroll
    for (int u = 0; u < 4; u++) {
        int e = u * 256 + tid;
        int dv = e >> 4, pk = (e & 15) * 4;
        ushort4 o;
        o.x = t[(pk + 0) * 68 + dv];
        o.y = t[(pk + 1) * 68 + dv];
        o.z = t[(pk + 2) * 68 + dv];
        o.w = t[(pk + 3) * 68 + dv];
        *(ushort4*)(VT + base + (long)dv * 2048 + p0 + pk) = o;
    }
}

// 128x128-tile GEMM, BK=32, 4 waves (2x2). Register-prefetch + dbuf LDS,
// one barrier per K-iteration (R7-proven).
// mode 0 (QKV, N=3072): which = n0g>>10 selects outQ/outK/outV; Q scaled 0.125.
// mode 1 (out-proj, N=1024): outQ = bf16(acc + bias + resid).
__global__ __launch_bounds__(256, 3) void gemm_kernel(
    const unsigned short* __restrict__ A,
    const unsigned short* __restrict__ Bt,
    const float* __restrict__ b0, const float* __restrict__ b1, const float* __restrict__ b2,
    unsigned short* __restrict__ outQ, unsigned short* __restrict__ outK,
    unsigned short* __restrict__ outV,
    const float* __restrict__ resid, int mode)
{
    __shared__ __align__(16) unsigned short As[2][128 * 32];
    __shared__ __align__(16) unsigned short Bs[2][128 * 32];
    const int tid = threadIdx.x;
    const int lane = tid & 63, wave = tid >> 6;
    const int quad = lane >> 4, l16 = lane & 15;
    const int wm = wave >> 1, wn = wave & 1;
    const int row0 = blockIdx.y * 128, n0g = blockIdx.x * 128;

    const int sr = tid >> 2;
    const int sc = (tid & 3) * 8;
    const unsigned short* Ag0 = A + (size_t)(row0 + sr) * 1024 + sc;
    const unsigned short* Ag1 = A + (size_t)(row0 + 64 + sr) * 1024 + sc;
    const unsigned short* Bg0 = Bt + (size_t)(n0g + sr) * 1024 + sc;
    const unsigned short* Bg1 = Bt + (size_t)(n0g + 64 + sr) * 1024 + sc;

    {
        ushort8 a0 = *(const ushort8*)(Ag0);
        ushort8 a1 = *(const ushort8*)(Ag1);
        ushort8 bv0 = *(const ushort8*)(Bg0);
        ushort8 bv1 = *(const ushort8*)(Bg1);
        *(ushort8*)(As[0] + sr * 32 + sc) = a0;
        *(ushort8*)(As[0] + (64 + sr) * 32 + sc) = a1;
        *(ushort8*)(Bs[0] + sr * 32 + sc) = bv0;
        *(ushort8*)(Bs[0] + (64 + sr) * 32 + sc) = bv1;
    }
    __syncthreads();

    f32x4 acc[4][4] = {};
    #pragma unroll 2
    for (int it = 0; it < 32; ++it) {
        const int cur = it & 1;
        ushort8 na0, na1, nb0, nb1;
        if (it < 31) {
            const int k0 = (it + 1) * 32;
            na0 = *(const ushort8*)(Ag0 + k0);
            na1 = *(const ushort8*)(Ag1 + k0);
            nb0 = *(const ushort8*)(Bg0 + k0);
            nb1 = *(const ushort8*)(Bg1 + k0);
        }
        bf16x8 af[4], bfr[4];
        #pragma unroll
        for (int i = 0; i < 4; i++)
            af[i] = *(const bf16x8*)(As[cur] + (wm * 64 + i * 16 + l16) * 32 + quad * 8);
        #pragma unroll
        for (int j = 0; j < 4; j++)
            bfr[j] = *(const bf16x8*)(Bs[cur] + (wn * 64 + j * 16 + l16) * 32 + quad * 8);
        #pragma unroll
        for (int i = 0; i < 4; i++)
            #pragma unroll
            for (int j = 0; j < 4; j++)
                acc[i][j] = __builtin_amdgcn_mfma_f32_16x16x32_bf16(af[i], bfr[j], acc[i][j], 0, 0, 0);
        if (it < 31) {
            const int nxt = cur ^ 1;
            *(ushort8*)(As[nxt] + sr * 32 + sc) = na0;
            *(ushort8*)(As[nxt] + (64 + sr) * 32 + sc) = na1;
            *(ushort8*)(Bs[nxt] + sr * 32 + sc) = nb0;
            *(ushort8*)(Bs[nxt] + (64 + sr) * 32 + sc) = nb1;
            __syncthreads();
        }
    }

    if (mode == 0) {
        const int which = n0g >> 10;
        const float* bp = (which == 0) ? b0 : (which == 1) ? b1 : b2;
        unsigned short* op = (which == 0) ? outQ : (which == 1) ? outK : outV;
        const float scl = (which == 0) ? 0.125f : 1.0f;
        #pragma unroll
        for (int i = 0; i < 4; i++)
            #pragma unroll
            for (int j = 0; j < 4; j++) {
                int c = (n0g + wn * 64 + j * 16 + l16) & 1023;
                float bj = bp[c];
                #pragma unroll
                for (int r = 0; r < 4; r++) {
                    int r_g = row0 + wm * 64 + i * 16 + quad * 4 + r;
                    op[(size_t)r_g * 1024 + c] = f2bf((acc[i][j][r] + bj) * scl);
                }
            }
    } else {
        #pragma unroll
        for (int i = 0; i < 4; i++)
            #pragma unroll
            for (int j = 0; j < 4; j++) {
                int c_g = n0g + wn * 64 + j * 16 + l16;
                float bj = b0[c_g];
                #pragma unroll
                for (int r = 0; r < 4; r++) {
                    int r_g = row0 + wm * 64 + i * 16 + quad * 4 + r;
                    size_t idx = (size_t)r_g * 1024 + c_g;
                    outQ[idx] = f2bf(acc[i][j][r] + bj + resid[idx]);
                }
            }
    }
}

// Causal flash attention, S^T formulation, in-register P (no Pt LDS).
// R12 structure: 64-row Q blocks, 4 waves x 16 q-rows, Kt+Vt LDS with
// register-prefetch dbuf. y->qb balance permutation: stride-256 CU sets
// get qb {31-y0, y0, 23-y0, y0+8} = exactly 34 tiles each.
// s_setprio(1) wraps the MFMA clusters (T5): the CU's 4 resident blocks
// run desynced nt -> scheduler favors MFMA-issuing waves (m191 regime).
// P redistribution quad-exchange (verified R11/R12):
//   cvt_pk_bf16 pairs (E from even c, O from odd c), then
//   permlane32_swap + permlane16_swap: (E0,O0)->(word0,word2),
//   (E1,O1)->(word1,word3).
__global__ __launch_bounds__(256, 4) void flash_kernel(
    const unsigned short* __restrict__ Q,
    const unsigned short* __restrict__ K,
    const unsigned short* __restrict__ VT,
    unsigned short* __restrict__ Ctx)
{
    __shared__ __align__(16) unsigned short Kt[128 * 72];    // [kpos][dk]
    __shared__ __align__(16) unsigned short Vt[64 * 136];    // [dv][kpos]
    const int tid = threadIdx.x;
    const int lane = tid & 63, wave = tid >> 6;
    const int quad = lane >> 4, l16 = lane & 15;
    const int y = blockIdx.y;
    const int qb = (y < 8) ? (31 - y) : (y < 16) ? (y - 8)
                 : (y < 24) ? (39 - y) : (y - 16);
    const int q0 = qb * 64;
    const long base = (long)blockIdx.x * 131072;
    const int nt = (qb + 2) >> 1;

    bf16x8 qa[2];
    #pragma unroll
    for (int h = 0; h < 2; h++)
        qa[h] = *(const bf16x8*)(Q + base + (q0 + wave * 16 + l16) * 64 + h * 32 + quad * 8);

    f32x4 o[4] = {};
    float l_one = 0.f;
    const int qpos = q0 + wave * 16 + l16;

    // stage tile 0
    #pragma unroll
    for (int u = 0; u < 4; u++) {
        int e = u * 256 + tid;
        int r = e >> 3, c = (e & 7) * 8;
        *(ushort8*)(Kt + r * 72 + c) = *(const ushort8*)(K + base + (long)r * 64 + c);
        int dv = e >> 4, kc = (e & 15) * 8;
        *(ushort8*)(Vt + dv * 136 + kc) = *(const ushort8*)(VT + base + (long)dv * 2048 + kc);
    }
    __syncthreads();

    for (int t = 0; t < nt; t++) {
        ushort8 nk[4], nv[4];
        if (t + 1 < nt) {
            const int k1 = (t + 1) * 128;
            #pragma unroll
            for (int u = 0; u < 4; u++) {
                int e = u * 256 + tid;
                int r = e >> 3, c = (e & 7) * 8;
                nk[u] = *(const ushort8*)(K + base + (long)(k1 + r) * 64 + c);
                int dv = e >> 4, kc = (e & 15) * 8;
                nv[u] = *(const ushort8*)(VT + base + (long)dv * 2048 + k1 + kc);
            }
        }
        const int k0 = t * 128;
        const bool diag = (t == nt - 1);
        // wave w needs kpos up to q0+16w+15; pairs kk<=kkmax.
        const int kkmax = diag ? ((q0 - k0 + wave * 16 + 15) >> 5) : 3;

        #pragma unroll
        for (int kk = 0; kk < 4; kk++) {
            if (kk <= kkmax) {
                const int cE = kk * 2, cO = kk * 2 + 1;
                f32x4 aE = {}, aO = {};
                __builtin_amdgcn_s_setprio(1);
                {
                    bf16x8 kb0 = *(const bf16x8*)(Kt + (cE * 16 + l16) * 72 + quad * 8);
                    bf16x8 kb1 = *(const bf16x8*)(Kt + (cE * 16 + l16) * 72 + 32 + quad * 8);
                    aE = __builtin_amdgcn_mfma_f32_16x16x32_bf16(kb0, qa[0], aE, 0, 0, 0);
                    aE = __builtin_amdgcn_mfma_f32_16x16x32_bf16(kb1, qa[1], aE, 0, 0, 0);
                }
                {
                    bf16x8 kb0 = *(const bf16x8*)(Kt + (cO * 16 + l16) * 72 + quad * 8);
                    bf16x8 kb1 = *(const bf16x8*)(Kt + (cO * 16 + l16) * 72 + 32 + quad * 8);
                    aO = __builtin_amdgcn_mfma_f32_16x16x32_bf16(kb0, qa[0], aO, 0, 0, 0);
                    aO = __builtin_amdgcn_mfma_f32_16x16x32_bf16(kb1, qa[1], aO, 0, 0, 0);
                }
                __builtin_amdgcn_s_setprio(0);
                float pE[4], pO[4];
                #pragma unroll
                for (int r = 0; r < 4; r++) {
                    float e1 = __expf(aE[r]);
                    float e2 = __expf(aO[r]);
                    if (diag) {
                        int kE = k0 + cE * 16 + quad * 4 + r;
                        int kO = k0 + cO * 16 + quad * 4 + r;
                        e1 = (kE > qpos) ? 0.f : e1;
                        e2 = (kO > qpos) ? 0.f : e2;
                    }
                    pE[r] = e1; pO[r] = e2;
                }
                l_one += (pE[0] + pE[1]) + (pE[2] + pE[3])
                       + (pO[0] + pO[1]) + (pO[2] + pO[3]);
                unsigned w0 = cvt_pk_bf16(pE[0], pE[1]);   // E0
                unsigned w1 = cvt_pk_bf16(pE[2], pE[3]);   // E1
                unsigned w2 = cvt_pk_bf16(pO[0], pO[1]);   // O0
                unsigned w3 = cvt_pk_bf16(pO[2], pO[3]);   // O1
                // (E0,O0) -> word0/word2 ; (E1,O1) -> word1/word3
                asm("v_permlane32_swap_b32 %0, %1" : "+v"(w0), "+v"(w2));
                asm("v_permlane16_swap_b32 %0, %1" : "+v"(w0), "+v"(w2));
                asm("v_permlane32_swap_b32 %0, %1" : "+v"(w1), "+v"(w3));
                asm("v_permlane16_swap_b32 %0, %1" : "+v"(w1), "+v"(w3));
                u32x4 pu;
                pu[0] = w0; pu[1] = w1; pu[2] = w2; pu[3] = w3;
                bf16x8 pa = __builtin_bit_cast(bf16x8, pu);
                __builtin_amdgcn_s_setprio(1);
                #pragma unroll
                for (int c2 = 0; c2 < 4; c2++) {
                    bf16x8 vb = *(const bf16x8*)(Vt + (c2 * 16 + l16) * 136 + kk * 32 + quad * 8);
                    o[c2] = __builtin_amdgcn_mfma_f32_16x16x32_bf16(pa, vb, o[c2], 0, 0, 0);
                }
                __builtin_amdgcn_s_setprio(0);
            }
        }
        __syncthreads();
        if (t + 1 < nt) {
            #pragma unroll
            for (int u = 0; u < 4; u++) {
                int e = u * 256 + tid;
                int r = e >> 3, c = (e & 7) * 8;
                *(ushort8*)(Kt + r * 72 + c) = nk[u];
                int dv = e >> 4, kc = (e & 15) * 8;
                *(ushort8*)(Vt + dv * 136 + kc) = nv[u];
            }
            __syncthreads();
        }
    }

    l_one += __shfl_xor(l_one, 16, 64);
    l_one += __shfl_xor(l_one, 32, 64);
    float rinv[4];
    #pragma unroll
    for (int r = 0; r < 4; r++)
        rinv[r] = 1.0f / __shfl(l_one, quad * 4 + r, 16);
    #pragma unroll
    for (int c2 = 0; c2 < 4; c2++)
        #pragma unroll
        for (int r = 0; r < 4; r++) {
            int row = q0 + wave * 16 + quad * 4 + r;
            Ctx[base + (long)row * 64 + c2 * 16 + l16] = f2bf(o[c2][r] * rinv[r]);
        }
}

// LayerNorm over bf16 input rows (out-proj+resid already applied), fp32 out.
__global__ __launch_bounds__(256) void ln_kernel(const unsigned short* __restrict__ inp,
                                                 const float* __restrict__ gamma,
                                                 const float* __restrict__ beta,
                                                 float* __restrict__ out)
{
    __shared__ float ssum[4], ssq[4];
    const int row = blockIdx.x;
    const int tid = threadIdx.x;
    ushort4 uv = ((const ushort4*)(inp + (size_t)row * 1024))[tid];
    float vx = bf2f(uv.x), vy = bf2f(uv.y), vz = bf2f(uv.z), vw = bf2f(uv.w);
    float s = vx + vy + vz + vw;
    float q = vx * vx + vy * vy + vz * vz + vw * vw;
    #pragma unroll
    for (int off = 32; off >= 1; off >>= 1) {
        s += __shfl_xor(s, off, 64);
        q += __shfl_xor(q, off, 64);
    }
    if ((tid & 63) == 0) { ssum[tid >> 6] = s; ssq[tid >> 6] = q; }
    __syncthreads();
    float ts = ssum[0] + ssum[1] + ssum[2] + ssum[3];
    float tq = ssq[0] + ssq[1] + ssq[2] + ssq[3];
    float mean = ts * (1.f / 1024.f);
    float var = tq * (1.f / 1024.f) - mean * mean;
    float rinv = rsqrtf(var + 1e-5f);
    float4 g = ((const float4*)gamma)[tid];
    float4 b = ((const float4*)beta)[tid];
    float4 o;
    o.x = (vx - mean) * rinv * g.x + b.x;
    o.y = (vy - mean) * rinv * g.y + b.y;
    o.z = (vz - mean) * rinv * g.z + b.z;
    o.w = (vw - mean) * rinv * g.w + b.w;
    ((float4*)(out + (size_t)row * 1024))[tid] = o;
}

extern "C" void kernel_launch(void* const* d_in, const int* in_sizes, int n_in,
                              void* d_out, int out_size, void* d_ws, size_t ws_size,
                              hipStream_t stream) {
    const float* x     = (const float*)d_in[0];
    const float* Wk    = (const float*)d_in[1];
    const float* bk    = (const float*)d_in[2];
    const float* Wq    = (const float*)d_in[3];
    const float* bq    = (const float*)d_in[4];
    const float* Wv    = (const float*)d_in[5];
    const float* bv    = (const float*)d_in[6];
    const float* Wo    = (const float*)d_in[7];
    const float* bo    = (const float*)d_in[8];
    const float* gamma = (const float*)d_in[9];
    const float* beta  = (const float*)d_in[10];
    float* out = (float*)d_out;

    char* ws = (char*)d_ws;
    unsigned short* xb    = (unsigned short*)(ws);                 // 8 MB
    unsigned short* WqkvT = (unsigned short*)(ws + (8ull << 20));  // 8 MB (incl WoT at +6MB)
    unsigned short* Qb    = (unsigned short*)(ws + (16ull << 20)); // 8 MB
    unsigned short* Kb    = (unsigned short*)(ws + (24ull << 20)); // 8 MB
    unsigned short* VbT   = (unsigned short*)(ws + (32ull << 20)); // 8 MB
    unsigned short* Cb    = (unsigned short*)(ws + (40ull << 20)); // 8 MB
    unsigned short* outp  = (unsigned short*)(ws + (48ull << 20)); // 8 MB bf16
    unsigned short* WoT   = WqkvT + (3u << 20);
    unsigned short* Vbn   = Cb;  // V normal layout, dead before flash writes Cb

    dim3 pgrid(16, 16, 5);
    prep_kernel<<<pgrid, 256, 0, stream>>>(x, Wq, Wk, Wv, Wo, xb, WqkvT);

    dim3 qkvgrid(24, 32);
    gemm_kernel<<<qkvgrid, 256, 0, stream>>>(xb, WqkvT, bq, bk, bv,
                                             Qb, Kb, Vbn, nullptr, 0);

    dim3 vgrid(32, 32);
    vtrans_kernel<<<vgrid, 256, 0, stream>>>(Vbn, VbT);

    dim3 fgrid(32, 32);
    flash_kernel<<<fgrid, 256, 0, stream>>>(Qb, Kb, VbT, Cb);

    dim3 ogrid(8, 32);
    gemm_kernel<<<ogrid, 256, 0, stream>>>(Cb, WoT, bo, nullptr, nullptr,
                                           outp, nullptr, nullptr, x, 1);

    ln_kernel<<<4096, 256, 0, stream>>>(outp, gamma, beta, out);
}